// Round 3
// baseline (1458.023 us; speedup 1.0000x reference)
//
#include <hip/hip_runtime.h>

#define T_SEQ   1024
#define INDIM   6
#define HDIM    64
#define NPRED   10
#define CHNK    128
#define S0      104      // LDS row stride (elements) for h/x buffers
#define NROWS   8        // batch rows per workgroup (grid 512 = 2 blocks/CU)
#define BROWS   16       // buffer row capacity (MFMA tile N=16; rows 8-15 are dummies)
#define NXT     (NROWS * INDIM)   // threads carrying x-writes / FC head (48)

typedef __bf16         bf16x8 __attribute__((ext_vector_type(8)));
typedef float          f32x4  __attribute__((ext_vector_type(4)));
typedef float          f32x2  __attribute__((ext_vector_type(2)));
typedef unsigned short us4    __attribute__((ext_vector_type(4)));

// D = A*B + C with A = weight frag, B = h frag  ->  D[m=unit][n=batch row]
#define MFMA16(a, b, c) __builtin_amdgcn_mfma_f32_16x16x32_bf16((a), (b), (c), 0, 0, 0)

static __device__ __forceinline__ float bf2f(unsigned short b) {
  union { unsigned int u; float f; } v; v.u = ((unsigned int)b) << 16; return v.f;
}
// Native RNE f32->bf16 (ISel pairs these into v_cvt_pk_bf16_f32 on gfx950).
static __device__ __forceinline__ unsigned short f2bf(float f) {
  union { __bf16 b; unsigned short u; } v; v.b = (__bf16)f; return v.u;
}

// R3: R1 skeleton (layer-pipelined, 1 barrier/encoder step) but HALF the rows
// per block and TWICE the blocks: grid 512 = 2 blocks/CU = 4 waves/SIMD = 4
// independent recurrence chains per SIMD (two per block). The two co-resident
// blocks' barriers are independent, so one block's act/MFMA latency is hidden
// under the other block's work. MFMA runs N=8 useful of 16 (dummy rows 8-15
// stay zero -> finite, column-isolated). Per-element math identical
// (bit-exact canary: absmax must stay 0.0009765625).
template <bool F32>
__global__ __launch_bounds__(512, 4)
void lstm2_pipe(const void* __restrict__ xv,
                const void* __restrict__ Wih0v,
                const void* __restrict__ Whh0v,
                const void* __restrict__ bih0v,
                const void* __restrict__ bhh0v,
                const void* __restrict__ Wih1v,
                const void* __restrict__ Whh1v,
                const void* __restrict__ bih1v,
                const void* __restrict__ bhh1v,
                const void* __restrict__ fcwv,
                const void* __restrict__ fcbv,
                void* __restrict__ outv)
{
  // ---- dtype sniff (uniform) ----
  {
    const unsigned short* w0u = (const unsigned short*)Wih0v;
    int votes = 0;
#pragma unroll
    for (int i = 0; i < 16; ++i) {
      const unsigned e = (w0u[2 * i] >> 7) & 0xFF;
      votes += (e >= 0x80 || e <= 0x40) ? 1 : 0;
    }
    if ((votes >= 4) != F32) return;
  }

  // A0[b]: [row][k]: k 0..63 = h0 (unit-major), 64..69 = x, 70..95 zero pad.
  __shared__ __align__(16) unsigned short A0[2][BROWS * S0];
  __shared__ __align__(16) unsigned short A1[2][BROWS * S0];
  __shared__ __align__(16) unsigned short XB[NROWS * CHNK * INDIM];
  __shared__ __align__(16) unsigned short FCW[INDIM * HDIM];
  __shared__ float FCB[INDIM];

  const int tid   = threadIdx.x;
  const int lane  = tid & 63;
  const int wave  = tid >> 6;
  const bool isA  = (wave < 4);
  const int  wv4  = wave & 3;
  const int  q    = lane >> 4;
  const int  n    = lane & 15;          // batch row owned by this lane (D col)
  const int  u    = 16 * wv4 + n;       // index used for W/bias row addressing
  const int rbase = blockIdx.x * NROWS;

  {
    unsigned short* p0 = &A0[0][0];
    unsigned short* p1 = &A1[0][0];
    for (int i = tid; i < 2 * BROWS * S0; i += 512) { p0[i] = 0; p1[i] = 0; }
  }
  for (int i = tid; i < INDIM * HDIM; i += 512) {
    if constexpr (F32) FCW[i] = f2bf(((const float*)fcwv)[i]);
    else               FCW[i] = ((const unsigned short*)fcwv)[i];
  }
  if (tid < INDIM) {
    if constexpr (F32) FCB[tid] = ((const float*)fcbv)[tid];
    else               FCB[tid] = bf2f(((const unsigned short*)fcbv)[tid]);
  }

  auto ld1 = [&](const void* p, int i) -> float {
    if constexpr (F32) return ((const float*)p)[i];
    else               return bf2f(((const unsigned short*)p)[i]);
  };
  auto ld8 = [&](const void* W, int off) -> bf16x8 {
    union { unsigned short us[8]; bf16x8 v; } t;
    if constexpr (F32) {
      const float* p = (const float*)W + off;
#pragma unroll
      for (int j = 0; j < 8; ++j) t.us[j] = f2bf(p[j]);
    } else {
      t.v = *(const bf16x8*)((const unsigned short*)W + off);
    }
    return t.v;
  };

  auto load_chunk = [&](int t0c) {
    if constexpr (F32) {
      const char* xb = (const char*)xv;
      for (int c = tid; c < NROWS * 192; c += 512) {
        const int row = c / 192;
        const int off = c - row * 192;
        const float4 v = *(const float4*)(xb + (size_t)(rbase + row) * (T_SEQ * INDIM * 4)
                                             + (size_t)t0c * (INDIM * 4) + (size_t)off * 16);
        us4 o;
        o.x = f2bf(v.x); o.y = f2bf(v.y); o.z = f2bf(v.z); o.w = f2bf(v.w);
        *(us4*)((char*)XB + (size_t)c * 8) = o;
      }
    } else {
      const char* xb = (const char*)xv;
      for (int c = tid; c < NROWS * 96; c += 512) {
        const int row = c / 96;
        const int off = c - row * 96;
        const int4 v = *(const int4*)(xb + (size_t)(rbase + row) * (T_SEQ * INDIM * 2)
                                         + (size_t)t0c * (INDIM * 2) + (size_t)off * 16);
        *(int4*)((char*)XB + (size_t)c * 16) = v;
      }
    }
  };

  load_chunk(0);
  __syncthreads();

  const int xrow   = tid / INDIM;                 // valid for tid < NXT
  const int xk     = tid - xrow * INDIM;
  const int xWrOff = xrow * S0 + HDIM + xk;
  const int xbBase = xrow * (CHNK * INDIM) + xk;

  if (tid < NXT) A0[0][xWrOff] = XB[xbBase];      // x_0
  __syncthreads();

  const int aOff  = n * S0 + 8 * q;               // h frag (B-operand): row n, k 8q..
  const int hOffW = n * S0 + 16 * wv4 + 4 * q;    // packed h-write: row n, units 4q..4q+3
  const int bOff  = 16 * wv4 + 4 * q;             // bias vector base within gate block

  // cell state as two f32 pairs (cells 0,1 | 2,3) so act math stays packed
  f32x2 cc2[2]; cc2[0] = (f32x2){0.f, 0.f}; cc2[1] = (f32x2){0.f, 0.f};

  // bias vector for gate block gt: b[64gt + bOff .. +3]
  auto ldbias = [&](const void* b1, const void* b2, int gt) -> f32x4 {
    f32x4 r;
#pragma unroll
    for (int j = 0; j < 4; ++j)
      r[j] = ld1(b1, 64 * gt + bOff + j) + ld1(b2, 64 * gt + bOff + j);
    return r;
  };

  // 7-trans combined-rcp cell update, packed-f32 (v_pk_*) elementwise math,
  // native cvt_pk bf16 packing, one b64 h-write.
  const f32x2 C1   = {-1.442695040888963f, -1.442695040888963f};
  const f32x2 C2   = {-2.885390081777927f, -2.885390081777927f};
  const f32x2 onep = {1.0f, 1.0f};

  auto act4 = [&](const f32x4 gI, const f32x4 gF, const f32x4 gG, const f32x4 gO,
                  unsigned short* dst) {
    unsigned int w2[2];
#pragma unroll
    for (int p = 0; p < 2; ++p) {
      f32x2 vI, vF, vG, vO;
      vI.x = gI[2 * p]; vI.y = gI[2 * p + 1];
      vF.x = gF[2 * p]; vF.y = gF[2 * p + 1];
      vG.x = gG[2 * p]; vG.y = gG[2 * p + 1];
      vO.x = gO[2 * p]; vO.y = gO[2 * p + 1];
      const f32x2 aF = vF * C1;
      const f32x2 aI = vI * C1;
      const f32x2 aG = vG * C2;
      const f32x2 aO = vO * C1;
      f32x2 Ae, Be, Ge, Oe;
      Ae.x = __builtin_amdgcn_exp2f(aF.x); Ae.y = __builtin_amdgcn_exp2f(aF.y);
      Be.x = __builtin_amdgcn_exp2f(aI.x); Be.y = __builtin_amdgcn_exp2f(aI.y);
      Ge.x = __builtin_amdgcn_exp2f(aG.x); Ge.y = __builtin_amdgcn_exp2f(aG.y);
      Oe.x = __builtin_amdgcn_exp2f(aO.x); Oe.y = __builtin_amdgcn_exp2f(aO.y);
      const f32x2 M1 = (onep + Be) * (onep + Ge);
      const f32x2 t2 = onep + Ae;
      const f32x2 nm = cc2[p] * M1 + (onep - Ge) * t2;
      const f32x2 den = t2 * M1;
      f32x2 rd; rd.x = __builtin_amdgcn_rcpf(den.x); rd.y = __builtin_amdgcn_rcpf(den.y);
      const f32x2 cn = nm * rd;
      cc2[p] = cn;
      const f32x2 aE = cn * C2;
      f32x2 Ee; Ee.x = __builtin_amdgcn_exp2f(aE.x); Ee.y = __builtin_amdgcn_exp2f(aE.y);
      const f32x2 dh = (onep + Ee) * (onep + Oe);
      f32x2 rh; rh.x = __builtin_amdgcn_rcpf(dh.x); rh.y = __builtin_amdgcn_rcpf(dh.y);
      const f32x2 hv = (onep - Ee) * rh;
      w2[p] = (unsigned int)f2bf(hv.x) | ((unsigned int)f2bf(hv.y) << 16);
    }
    uint2 pk; pk.x = w2[0]; pk.y = w2[1];
    *(uint2*)(dst + hOffW) = pk;
  };

  unsigned short* H0 = &A0[0][0];    // after encoder: h0(1023) ++ x(1023)
  unsigned short* H1 = &A1[1][0];    // after encoder: h1(1023)

  if (isA) {
    // ================= layer-0 engine =================
    bf16x8 WA[12]; f32x4 bvA[4];
#pragma unroll
    for (int gt = 0; gt < 4; ++gt) {
      const int col = 64 * gt + u;
      WA[gt * 3 + 0] = ld8(Whh0v, col * HDIM + 8 * q);       // A-frag: W[unit][k]
      WA[gt * 3 + 1] = ld8(Whh0v, col * HDIM + 32 + 8 * q);
      union { unsigned short us[8]; bf16x8 v; } t2;
#pragma unroll
      for (int j = 0; j < 8; ++j) t2.us[j] = 0;
      if (q == 0) {
#pragma unroll
        for (int j = 0; j < INDIM; ++j) t2.us[j] = f2bf(ld1(Wih0v, col * INDIM + j));
      }
      WA[gt * 3 + 2] = t2.v;
      bvA[gt] = ldbias(bih0v, bhh0v, gt);
    }

    int t0v = 0;
    for (int i = 0; i <= T_SEQ; ++i) {
      if (((i + 1) & (CHNK - 1)) == 0 && (i + 1) < T_SEQ) {
        load_chunk(i + 1);
        __syncthreads();
        t0v = i + 1;
      }
      const int cur = i & 1;
      if (i < T_SEQ) {
        const unsigned short* A0c = &A0[cur][0];
        unsigned short*       A0n = &A0[cur ^ 1][0];
        // x-write for the NEXT step is h-independent: issue it first so its
        // LDS latency hides under the MFMA/act chain instead of the tail.
        const int srct = (i + 1 < T_SEQ) ? (i + 1) : (T_SEQ - 1);
        if (tid < NXT) A0n[xWrOff] = XB[xbBase + (srct - t0v) * INDIM];
        const bf16x8 f0 = *(const bf16x8*)(A0c + aOff);
        const bf16x8 f1 = *(const bf16x8*)(A0c + aOff + 32);
        const bf16x8 f2 = *(const bf16x8*)(A0c + aOff + 64);
        f32x4 g0 = MFMA16(WA[0], f0, bvA[0]); g0 = MFMA16(WA[1],  f1, g0); g0 = MFMA16(WA[2],  f2, g0);
        f32x4 g1 = MFMA16(WA[3], f0, bvA[1]); g1 = MFMA16(WA[4],  f1, g1); g1 = MFMA16(WA[5],  f2, g1);
        f32x4 g2 = MFMA16(WA[6], f0, bvA[2]); g2 = MFMA16(WA[7],  f1, g2); g2 = MFMA16(WA[8],  f2, g2);
        f32x4 g3 = MFMA16(WA[9], f0, bvA[3]); g3 = MFMA16(WA[10], f1, g3); g3 = MFMA16(WA[11], f2, g3);
        act4(g0, g1, g2, g3, A0n);
      }
      __syncthreads();
    }
    // decoder, engine A (4 barriers/step, mirrored in B)
    for (int d = 0; d < NPRED; ++d) {
      const bf16x8 fa0 = *(const bf16x8*)(H0 + aOff);
      const bf16x8 fa1 = *(const bf16x8*)(H0 + aOff + 32);
      const bf16x8 fa2 = *(const bf16x8*)(H0 + aOff + 64);
      __syncthreads();                      // ph1
      {
        f32x4 g0 = MFMA16(WA[0], fa0, bvA[0]); g0 = MFMA16(WA[1],  fa1, g0); g0 = MFMA16(WA[2],  fa2, g0);
        f32x4 g1 = MFMA16(WA[3], fa0, bvA[1]); g1 = MFMA16(WA[4],  fa1, g1); g1 = MFMA16(WA[5],  fa2, g1);
        f32x4 g2 = MFMA16(WA[6], fa0, bvA[2]); g2 = MFMA16(WA[7],  fa1, g2); g2 = MFMA16(WA[8],  fa2, g2);
        f32x4 g3 = MFMA16(WA[9], fa0, bvA[3]); g3 = MFMA16(WA[10], fa1, g3); g3 = MFMA16(WA[11], fa2, g3);
        act4(g0, g1, g2, g3, H0);
      }
      __syncthreads();                      // ph2
      __syncthreads();                      // ph3 (B computes h1)
      if (tid < NXT) {                      // ph4: FC head + feedback
        const unsigned short* h1row = H1 + xrow * S0;
        const int4* hp = (const int4*)h1row;
        const int4* wp = (const int4*)(&FCW[xk * HDIM]);
        float s = FCB[xk];
#pragma unroll
        for (int i8 = 0; i8 < 8; ++i8) {
          const int4 hv = hp[i8];
          const int4 wv2 = wp[i8];
          const unsigned int hu[4] = {(unsigned)hv.x, (unsigned)hv.y, (unsigned)hv.z, (unsigned)hv.w};
          const unsigned int wu[4] = {(unsigned)wv2.x, (unsigned)wv2.y, (unsigned)wv2.z, (unsigned)wv2.w};
#pragma unroll
          for (int k2 = 0; k2 < 4; ++k2) {
            union { unsigned int uu; float ff; } hl, hh2, wl, wh;
            hl.uu = hu[k2] << 16; hh2.uu = hu[k2] & 0xFFFF0000u;
            wl.uu = wu[k2] << 16; wh.uu  = wu[k2] & 0xFFFF0000u;
            s += hl.ff * wl.ff + hh2.ff * wh.ff;
          }
        }
        const unsigned short pb = f2bf(s);
        const size_t idx = (size_t)(rbase + xrow) * (NPRED * INDIM) + (size_t)d * INDIM + xk;
        if constexpr (F32) ((float*)outv)[idx] = s;
        else               ((unsigned short*)outv)[idx] = pb;
        H0[xWrOff] = pb;
      }
      __syncthreads();                      // ph4 end
    }
  } else {
    // ================= layer-1 engine (lag 1) =================
    bf16x8 WB[16]; f32x4 bvB[4];
#pragma unroll
    for (int gt = 0; gt < 4; ++gt) {
      const int col = 64 * gt + u;
      WB[gt * 4 + 0] = ld8(Wih1v, col * HDIM + 8 * q);
      WB[gt * 4 + 1] = ld8(Wih1v, col * HDIM + 32 + 8 * q);
      WB[gt * 4 + 2] = ld8(Whh1v, col * HDIM + 8 * q);
      WB[gt * 4 + 3] = ld8(Whh1v, col * HDIM + 32 + 8 * q);
      bvB[gt] = ldbias(bih1v, bhh1v, gt);
    }

    for (int i = 0; i <= T_SEQ; ++i) {
      if (((i + 1) & (CHNK - 1)) == 0 && (i + 1) < T_SEQ) {
        load_chunk(i + 1);
        __syncthreads();
      }
      const int cur = i & 1;
      if (i >= 1) {
        const unsigned short* A0c = &A0[cur][0];
        const unsigned short* A1c = &A1[cur][0];
        unsigned short*       A1n = &A1[cur ^ 1][0];
        const bf16x8 h0a = *(const bf16x8*)(A0c + aOff);
        const bf16x8 h0b = *(const bf16x8*)(A0c + aOff + 32);
        const bf16x8 r0  = *(const bf16x8*)(A1c + aOff);
        const bf16x8 r1  = *(const bf16x8*)(A1c + aOff + 32);
        f32x4 g0 = MFMA16(WB[0],  h0a, bvB[0]); g0 = MFMA16(WB[1],  h0b, g0); g0 = MFMA16(WB[2],  r0, g0); g0 = MFMA16(WB[3],  r1, g0);
        f32x4 g1 = MFMA16(WB[4],  h0a, bvB[1]); g1 = MFMA16(WB[5],  h0b, g1); g1 = MFMA16(WB[6],  r0, g1); g1 = MFMA16(WB[7],  r1, g1);
        f32x4 g2 = MFMA16(WB[8],  h0a, bvB[2]); g2 = MFMA16(WB[9],  h0b, g2); g2 = MFMA16(WB[10], r0, g2); g2 = MFMA16(WB[11], r1, g2);
        f32x4 g3 = MFMA16(WB[12], h0a, bvB[3]); g3 = MFMA16(WB[13], h0b, g3); g3 = MFMA16(WB[14], r0, g3); g3 = MFMA16(WB[15], r1, g3);
        act4(g0, g1, g2, g3, A1n);
      }
      __syncthreads();
    }
    // decoder, engine B (4 barriers/step, mirrored with A)
    for (int d = 0; d < NPRED; ++d) {
      const bf16x8 fr0 = *(const bf16x8*)(H1 + aOff);
      const bf16x8 fr1 = *(const bf16x8*)(H1 + aOff + 32);
      __syncthreads();                      // ph1
      __syncthreads();                      // ph2 (A computes h0)
      {
        const bf16x8 h0a = *(const bf16x8*)(H0 + aOff);
        const bf16x8 h0b = *(const bf16x8*)(H0 + aOff + 32);
        f32x4 g0 = MFMA16(WB[0],  h0a, bvB[0]); g0 = MFMA16(WB[1],  h0b, g0); g0 = MFMA16(WB[2],  fr0, g0); g0 = MFMA16(WB[3],  fr1, g0);
        f32x4 g1 = MFMA16(WB[4],  h0a, bvB[1]); g1 = MFMA16(WB[5],  h0b, g1); g1 = MFMA16(WB[6],  fr0, g1); g1 = MFMA16(WB[7],  fr1, g1);
        f32x4 g2 = MFMA16(WB[8],  h0a, bvB[2]); g2 = MFMA16(WB[9],  h0b, g2); g2 = MFMA16(WB[10], fr0, g2); g2 = MFMA16(WB[11], fr1, g2);
        f32x4 g3 = MFMA16(WB[12], h0a, bvB[3]); g3 = MFMA16(WB[13], h0b, g3); g3 = MFMA16(WB[14], fr0, g3); g3 = MFMA16(WB[15], fr1, g3);
        act4(g0, g1, g2, g3, H1);
      }
      __syncthreads();                      // ph3
      __syncthreads();                      // ph4 (A does FC head)
    }
  }
}

extern "C" void kernel_launch(void* const* d_in, const int* in_sizes, int n_in,
                              void* d_out, int out_size, void* d_ws, size_t ws_size,
                              hipStream_t stream) {
  (void)in_sizes; (void)n_in; (void)d_ws; (void)ws_size; (void)out_size;
  const void* x    = d_in[0];
  const void* Wih0 = d_in[1];
  const void* Whh0 = d_in[2];
  const void* bih0 = d_in[3];
  const void* bhh0 = d_in[4];
  const void* Wih1 = d_in[5];
  const void* Whh1 = d_in[6];
  const void* bih1 = d_in[7];
  const void* bhh1 = d_in[8];
  const void* fcw  = d_in[9];
  const void* fcb  = d_in[10];
  // Exactly one instance does the work (device-side dtype sniff).
  lstm2_pipe<true><<<dim3(4096 / NROWS), dim3(512), 0, stream>>>(
      x, Wih0, Whh0, bih0, bhh0, Wih1, Whh1, bih1, bhh1, fcw, fcb, d_out);
  lstm2_pipe<false><<<dim3(4096 / NROWS), dim3(512), 0, stream>>>(
      x, Wih0, Whh0, bih0, bhh0, Wih1, Whh1, bih1, bhh1, fcw, fcb, d_out);
}

// Round 4
// 1145.491 us; speedup vs baseline: 1.2728x; 1.2728x over previous
//
#include <hip/hip_runtime.h>

#define T_SEQ   1024
#define INDIM   6
#define HDIM    64
#define NPRED   10
#define CHNK    128
#define S0      104      // LDS row stride (elements) for h/x buffers
#define NROWS   16       // batch rows per workgroup (grid 256 = 1 block/CU)

typedef __bf16         bf16x8 __attribute__((ext_vector_type(8)));
typedef float          f32x4  __attribute__((ext_vector_type(4)));
typedef float          f32x2  __attribute__((ext_vector_type(2)));
typedef unsigned short us4    __attribute__((ext_vector_type(4)));

// D = A*B + C with A = weight frag, B = h frag  ->  D[m=unit][n=batch row]
#define MFMA16(a, b, c) __builtin_amdgcn_mfma_f32_16x16x32_bf16((a), (b), (c), 0, 0, 0)

static __device__ __forceinline__ float bf2f(unsigned short b) {
  union { unsigned int u; float f; } v; v.u = ((unsigned int)b) << 16; return v.f;
}
// Native RNE f32->bf16 (ISel pairs these into v_cvt_pk_bf16_f32 on gfx950).
static __device__ __forceinline__ unsigned short f2bf(float f) {
  union { __bf16 b; unsigned short u; } v; v.b = (__bf16)f; return v.u;
}
static __device__ __forceinline__ int imin(int a, int b) { return a < b ? a : b; }

// R4: R1 engine split (4 A-waves = layer0, 4 B-waves = layer1) but the
// per-step __syncthreads is replaced by one-directional LDS flag sync:
//   A0 = 4-slot ring: step t writes h0(t) + x(t+1) into slot t%4.
//   A1 = 2-slot ring: B step t writes h1(t) into slot t%2.
//   aflag[w]=t+1 when A-wave w finished step t; bflag likewise.
//   A-step t waits: min(aflag)>=t (peers), min(bflag)>=t-3 (ring credit).
//   B-step t waits: min(aflag)>=t+1 (h0(t) ready), min(bflag)>=t (peers).
// Release/acquire via __threadfence_block() around flag ops. One-directional
// + monotone counters -> no deadlock; chunk-staging keeps full barriers
// (every 128 steps) which also re-bounds drift. Per-element math identical
// (bit-exact canary: absmax must stay 0.0009765625).
template <bool F32>
__global__ __launch_bounds__(512, 2)
void lstm2_pipe(const void* __restrict__ xv,
                const void* __restrict__ Wih0v,
                const void* __restrict__ Whh0v,
                const void* __restrict__ bih0v,
                const void* __restrict__ bhh0v,
                const void* __restrict__ Wih1v,
                const void* __restrict__ Whh1v,
                const void* __restrict__ bih1v,
                const void* __restrict__ bhh1v,
                const void* __restrict__ fcwv,
                const void* __restrict__ fcbv,
                void* __restrict__ outv)
{
  // ---- dtype sniff (uniform) ----
  {
    const unsigned short* w0u = (const unsigned short*)Wih0v;
    int votes = 0;
#pragma unroll
    for (int i = 0; i < 16; ++i) {
      const unsigned e = (w0u[2 * i] >> 7) & 0xFF;
      votes += (e >= 0x80 || e <= 0x40) ? 1 : 0;
    }
    if ((votes >= 4) != F32) return;
  }

  // A0 ring: [slot][row][k]: k 0..63 = h0 (unit-major), 64..69 = x, 70..95 pad=0.
  __shared__ __align__(16) unsigned short A0[4][NROWS * S0];
  __shared__ __align__(16) unsigned short A1[2][NROWS * S0];
  __shared__ __align__(16) unsigned short XB[NROWS * CHNK * INDIM];
  __shared__ __align__(16) unsigned short FCW[INDIM * HDIM];
  __shared__ float FCB[INDIM];
  __shared__ int FLG[8];   // [0..3] = aflag, [4..7] = bflag

  const int tid   = threadIdx.x;
  const int lane  = tid & 63;
  const int wave  = tid >> 6;
  const bool isA  = (wave < 4);
  const int  wv4  = wave & 3;
  const int  q    = lane >> 4;
  const int  n    = lane & 15;          // batch row owned by this lane (D col)
  const int  u    = 16 * wv4 + n;       // index used for W/bias row addressing
  const int rbase = blockIdx.x * NROWS;

  {
    unsigned short* p0 = &A0[0][0];
    unsigned short* p1 = &A1[0][0];
    for (int i = tid; i < 4 * NROWS * S0; i += 512) p0[i] = 0;
    for (int i = tid; i < 2 * NROWS * S0; i += 512) p1[i] = 0;
  }
  for (int i = tid; i < INDIM * HDIM; i += 512) {
    if constexpr (F32) FCW[i] = f2bf(((const float*)fcwv)[i]);
    else               FCW[i] = ((const unsigned short*)fcwv)[i];
  }
  if (tid < INDIM) {
    if constexpr (F32) FCB[tid] = ((const float*)fcbv)[tid];
    else               FCB[tid] = bf2f(((const unsigned short*)fcbv)[tid]);
  }
  if (tid < 8) FLG[tid] = 0;

  auto ld1 = [&](const void* p, int i) -> float {
    if constexpr (F32) return ((const float*)p)[i];
    else               return bf2f(((const unsigned short*)p)[i]);
  };
  auto ld8 = [&](const void* W, int off) -> bf16x8 {
    union { unsigned short us[8]; bf16x8 v; } t;
    if constexpr (F32) {
      const float* p = (const float*)W + off;
#pragma unroll
      for (int j = 0; j < 8; ++j) t.us[j] = f2bf(p[j]);
    } else {
      t.v = *(const bf16x8*)((const unsigned short*)W + off);
    }
    return t.v;
  };

  auto load_chunk = [&](int t0c) {
    if constexpr (F32) {
      const char* xb = (const char*)xv;
      for (int c = tid; c < NROWS * 192; c += 512) {
        const int row = c / 192;
        const int off = c - row * 192;
        const float4 v = *(const float4*)(xb + (size_t)(rbase + row) * (T_SEQ * INDIM * 4)
                                             + (size_t)t0c * (INDIM * 4) + (size_t)off * 16);
        us4 o;
        o.x = f2bf(v.x); o.y = f2bf(v.y); o.z = f2bf(v.z); o.w = f2bf(v.w);
        *(us4*)((char*)XB + (size_t)c * 8) = o;
      }
    } else {
      const char* xb = (const char*)xv;
      for (int c = tid; c < NROWS * 96; c += 512) {
        const int row = c / 96;
        const int off = c - row * 96;
        const int4 v = *(const int4*)(xb + (size_t)(rbase + row) * (T_SEQ * INDIM * 2)
                                         + (size_t)t0c * (INDIM * 2) + (size_t)off * 16);
        *(int4*)((char*)XB + (size_t)c * 16) = v;
      }
    }
  };

  load_chunk(0);
  __syncthreads();

  // decoder FC/feedback mapping (tid-based, barrier-protected)
  const int dxr    = tid / INDIM;                 // valid for tid < 96
  const int dxk    = tid - dxr * INDIM;
  const int dxWrOff= dxr * S0 + HDIM + dxk;

  if (tid < 96) A0[3][dxWrOff] = XB[dxr * (CHNK * INDIM) + dxk];   // x_0 -> slot 3
  __syncthreads();

  // encoder x-copy mapping: balanced across the 4 A-waves, lanes 0..23
  const int  xe     = wv4 * 24 + lane;            // 0..95 over A-waves
  const bool xact   = isA && (lane < 24);
  const int  exr    = xe / INDIM;
  const int  exk    = xe - exr * INDIM;
  const int  exWrOff= exr * S0 + HDIM + exk;
  const int  exbBase= exr * (CHNK * INDIM) + exk;

  const int aOff  = n * S0 + 8 * q;               // h frag (B-operand): row n, k 8q..
  const int hOffW = n * S0 + 16 * wv4 + 4 * q;    // packed h-write: row n, units 4q..4q+3
  const int bOff  = 16 * wv4 + 4 * q;             // bias vector base within gate block

  // flag sync helpers
  auto poll2 = [&](int ta, int tb) {
    volatile int* f = (volatile int*)FLG;
    for (;;) {
      const int a0 = f[0], a1 = f[1], a2 = f[2], a3 = f[3];
      const int b0 = f[4], b1 = f[5], b2 = f[6], b3 = f[7];
      const int am = imin(imin(a0, a1), imin(a2, a3));
      const int bm = imin(imin(b0, b1), imin(b2, b3));
      if (am >= ta && bm >= tb) break;
      __builtin_amdgcn_s_sleep(1);
    }
    __threadfence_block();   // acquire
  };
  auto post = [&](int idx, int val) {
    __threadfence_block();   // release (drains prior ds_writes)
    if (lane == 0) ((volatile int*)FLG)[idx] = val;
  };

  // cell state as two f32 pairs (cells 0,1 | 2,3) so act math stays packed
  f32x2 cc2[2]; cc2[0] = (f32x2){0.f, 0.f}; cc2[1] = (f32x2){0.f, 0.f};

  // bias vector for gate block gt: b[64gt + bOff .. +3]
  auto ldbias = [&](const void* b1, const void* b2, int gt) -> f32x4 {
    f32x4 r;
#pragma unroll
    for (int j = 0; j < 4; ++j)
      r[j] = ld1(b1, 64 * gt + bOff + j) + ld1(b2, 64 * gt + bOff + j);
    return r;
  };

  // 7-trans combined-rcp cell update, packed-f32 (v_pk_*) elementwise math,
  // native cvt_pk bf16 packing, one b64 h-write.
  const f32x2 C1   = {-1.442695040888963f, -1.442695040888963f};
  const f32x2 C2   = {-2.885390081777927f, -2.885390081777927f};
  const f32x2 onep = {1.0f, 1.0f};

  auto act4 = [&](const f32x4 gI, const f32x4 gF, const f32x4 gG, const f32x4 gO,
                  unsigned short* dst) {
    unsigned int w2[2];
#pragma unroll
    for (int p = 0; p < 2; ++p) {
      f32x2 vI, vF, vG, vO;
      vI.x = gI[2 * p]; vI.y = gI[2 * p + 1];
      vF.x = gF[2 * p]; vF.y = gF[2 * p + 1];
      vG.x = gG[2 * p]; vG.y = gG[2 * p + 1];
      vO.x = gO[2 * p]; vO.y = gO[2 * p + 1];
      const f32x2 aF = vF * C1;
      const f32x2 aI = vI * C1;
      const f32x2 aG = vG * C2;
      const f32x2 aO = vO * C1;
      f32x2 Ae, Be, Ge, Oe;
      Ae.x = __builtin_amdgcn_exp2f(aF.x); Ae.y = __builtin_amdgcn_exp2f(aF.y);
      Be.x = __builtin_amdgcn_exp2f(aI.x); Be.y = __builtin_amdgcn_exp2f(aI.y);
      Ge.x = __builtin_amdgcn_exp2f(aG.x); Ge.y = __builtin_amdgcn_exp2f(aG.y);
      Oe.x = __builtin_amdgcn_exp2f(aO.x); Oe.y = __builtin_amdgcn_exp2f(aO.y);
      const f32x2 M1 = (onep + Be) * (onep + Ge);
      const f32x2 t2 = onep + Ae;
      const f32x2 nm = cc2[p] * M1 + (onep - Ge) * t2;
      const f32x2 den = t2 * M1;
      f32x2 rd; rd.x = __builtin_amdgcn_rcpf(den.x); rd.y = __builtin_amdgcn_rcpf(den.y);
      const f32x2 cn = nm * rd;
      cc2[p] = cn;
      const f32x2 aE = cn * C2;
      f32x2 Ee; Ee.x = __builtin_amdgcn_exp2f(aE.x); Ee.y = __builtin_amdgcn_exp2f(aE.y);
      const f32x2 dh = (onep + Ee) * (onep + Oe);
      f32x2 rh; rh.x = __builtin_amdgcn_rcpf(dh.x); rh.y = __builtin_amdgcn_rcpf(dh.y);
      const f32x2 hv = (onep - Ee) * rh;
      w2[p] = (unsigned int)f2bf(hv.x) | ((unsigned int)f2bf(hv.y) << 16);
    }
    uint2 pk; pk.x = w2[0]; pk.y = w2[1];
    *(uint2*)(dst + hOffW) = pk;
  };

  // After the ring encoder: h0(1023)+x(1023) in A0[3], h1(1023) in A1[1].
  unsigned short* H0 = &A0[3][0];
  unsigned short* H1 = &A1[1][0];

  if (isA) {
    // ================= layer-0 engine =================
    bf16x8 WA[12]; f32x4 bvA[4];
#pragma unroll
    for (int gt = 0; gt < 4; ++gt) {
      const int col = 64 * gt + u;
      WA[gt * 3 + 0] = ld8(Whh0v, col * HDIM + 8 * q);       // A-frag: W[unit][k]
      WA[gt * 3 + 1] = ld8(Whh0v, col * HDIM + 32 + 8 * q);
      union { unsigned short us[8]; bf16x8 v; } t2;
#pragma unroll
      for (int j = 0; j < 8; ++j) t2.us[j] = 0;
      if (q == 0) {
#pragma unroll
        for (int j = 0; j < INDIM; ++j) t2.us[j] = f2bf(ld1(Wih0v, col * INDIM + j));
      }
      WA[gt * 3 + 2] = t2.v;
      bvA[gt] = ldbias(bih0v, bhh0v, gt);
    }

    int t0v = 0;
    for (int t = 0; t < T_SEQ; ++t) {
      if (((t + 1) & (CHNK - 1)) == 0 && (t + 1) < T_SEQ) {
        __syncthreads();
        load_chunk(t + 1);
        __syncthreads();
        t0v = t + 1;
      }
      poll2(t, t - 3);                          // peers done t-1; ring credit
      const unsigned short* A0c = &A0[(t + 3) & 3][0];   // h0(t-1) + x(t)
      unsigned short*       A0n = &A0[t & 3][0];         // h0(t) + x(t+1)
      const int srct = (t + 1 < T_SEQ) ? (t + 1) : (T_SEQ - 1);
      if (xact) A0n[exWrOff] = XB[exbBase + (srct - t0v) * INDIM];
      const bf16x8 f0 = *(const bf16x8*)(A0c + aOff);
      const bf16x8 f1 = *(const bf16x8*)(A0c + aOff + 32);
      const bf16x8 f2 = *(const bf16x8*)(A0c + aOff + 64);
      f32x4 g0 = MFMA16(WA[0], f0, bvA[0]); g0 = MFMA16(WA[1],  f1, g0); g0 = MFMA16(WA[2],  f2, g0);
      f32x4 g1 = MFMA16(WA[3], f0, bvA[1]); g1 = MFMA16(WA[4],  f1, g1); g1 = MFMA16(WA[5],  f2, g1);
      f32x4 g2 = MFMA16(WA[6], f0, bvA[2]); g2 = MFMA16(WA[7],  f1, g2); g2 = MFMA16(WA[8],  f2, g2);
      f32x4 g3 = MFMA16(WA[9], f0, bvA[3]); g3 = MFMA16(WA[10], f1, g3); g3 = MFMA16(WA[11], f2, g3);
      act4(g0, g1, g2, g3, A0n);
      post(wv4, t + 1);
    }
    __syncthreads();
    // decoder, engine A (4 barriers/step, mirrored in B)
    for (int d = 0; d < NPRED; ++d) {
      const bf16x8 fa0 = *(const bf16x8*)(H0 + aOff);
      const bf16x8 fa1 = *(const bf16x8*)(H0 + aOff + 32);
      const bf16x8 fa2 = *(const bf16x8*)(H0 + aOff + 64);
      __syncthreads();                      // ph1
      {
        f32x4 g0 = MFMA16(WA[0], fa0, bvA[0]); g0 = MFMA16(WA[1],  fa1, g0); g0 = MFMA16(WA[2],  fa2, g0);
        f32x4 g1 = MFMA16(WA[3], fa0, bvA[1]); g1 = MFMA16(WA[4],  fa1, g1); g1 = MFMA16(WA[5],  fa2, g1);
        f32x4 g2 = MFMA16(WA[6], fa0, bvA[2]); g2 = MFMA16(WA[7],  fa1, g2); g2 = MFMA16(WA[8],  fa2, g2);
        f32x4 g3 = MFMA16(WA[9], fa0, bvA[3]); g3 = MFMA16(WA[10], fa1, g3); g3 = MFMA16(WA[11], fa2, g3);
        act4(g0, g1, g2, g3, H0);
      }
      __syncthreads();                      // ph2
      __syncthreads();                      // ph3 (B computes h1)
      if (tid < 96) {                       // ph4: FC head + feedback
        const unsigned short* h1row = H1 + dxr * S0;
        const int4* hp = (const int4*)h1row;
        const int4* wp = (const int4*)(&FCW[dxk * HDIM]);
        float s = FCB[dxk];
#pragma unroll
        for (int i8 = 0; i8 < 8; ++i8) {
          const int4 hv = hp[i8];
          const int4 wv2 = wp[i8];
          const unsigned int hu[4] = {(unsigned)hv.x, (unsigned)hv.y, (unsigned)hv.z, (unsigned)hv.w};
          const unsigned int wu[4] = {(unsigned)wv2.x, (unsigned)wv2.y, (unsigned)wv2.z, (unsigned)wv2.w};
#pragma unroll
          for (int k2 = 0; k2 < 4; ++k2) {
            union { unsigned int uu; float ff; } hl, hh2, wl, wh;
            hl.uu = hu[k2] << 16; hh2.uu = hu[k2] & 0xFFFF0000u;
            wl.uu = wu[k2] << 16; wh.uu  = wu[k2] & 0xFFFF0000u;
            s += hl.ff * wl.ff + hh2.ff * wh.ff;
          }
        }
        const unsigned short pb = f2bf(s);
        const size_t idx = (size_t)(rbase + dxr) * (NPRED * INDIM) + (size_t)d * INDIM + dxk;
        if constexpr (F32) ((float*)outv)[idx] = s;
        else               ((unsigned short*)outv)[idx] = pb;
        H0[dxWrOff] = pb;
      }
      __syncthreads();                      // ph4 end
    }
  } else {
    // ================= layer-1 engine =================
    bf16x8 WB[16]; f32x4 bvB[4];
#pragma unroll
    for (int gt = 0; gt < 4; ++gt) {
      const int col = 64 * gt + u;
      WB[gt * 4 + 0] = ld8(Wih1v, col * HDIM + 8 * q);
      WB[gt * 4 + 1] = ld8(Wih1v, col * HDIM + 32 + 8 * q);
      WB[gt * 4 + 2] = ld8(Whh1v, col * HDIM + 8 * q);
      WB[gt * 4 + 3] = ld8(Whh1v, col * HDIM + 32 + 8 * q);
      bvB[gt] = ldbias(bih1v, bhh1v, gt);
    }

    for (int t = 0; t < T_SEQ; ++t) {
      if (((t + 1) & (CHNK - 1)) == 0 && (t + 1) < T_SEQ) {
        __syncthreads();
        load_chunk(t + 1);
        __syncthreads();
      }
      poll2(t + 1, t);                          // h0(t) ready; peers done t-1
      const unsigned short* A0c = &A0[t & 3][0];         // h0(t)
      const unsigned short* A1c = &A1[(t + 1) & 1][0];   // h1(t-1)
      unsigned short*       A1n = &A1[t & 1][0];         // h1(t)
      const bf16x8 h0a = *(const bf16x8*)(A0c + aOff);
      const bf16x8 h0b = *(const bf16x8*)(A0c + aOff + 32);
      const bf16x8 r0  = *(const bf16x8*)(A1c + aOff);
      const bf16x8 r1  = *(const bf16x8*)(A1c + aOff + 32);
      f32x4 g0 = MFMA16(WB[0],  h0a, bvB[0]); g0 = MFMA16(WB[1],  h0b, g0); g0 = MFMA16(WB[2],  r0, g0); g0 = MFMA16(WB[3],  r1, g0);
      f32x4 g1 = MFMA16(WB[4],  h0a, bvB[1]); g1 = MFMA16(WB[5],  h0b, g1); g1 = MFMA16(WB[6],  r0, g1); g1 = MFMA16(WB[7],  r1, g1);
      f32x4 g2 = MFMA16(WB[8],  h0a, bvB[2]); g2 = MFMA16(WB[9],  h0b, g2); g2 = MFMA16(WB[10], r0, g2); g2 = MFMA16(WB[11], r1, g2);
      f32x4 g3 = MFMA16(WB[12], h0a, bvB[3]); g3 = MFMA16(WB[13], h0b, g3); g3 = MFMA16(WB[14], r0, g3); g3 = MFMA16(WB[15], r1, g3);
      act4(g0, g1, g2, g3, A1n);
      post(4 + wv4, t + 1);
    }
    __syncthreads();
    // decoder, engine B (4 barriers/step, mirrored with A)
    for (int d = 0; d < NPRED; ++d) {
      const bf16x8 fr0 = *(const bf16x8*)(H1 + aOff);
      const bf16x8 fr1 = *(const bf16x8*)(H1 + aOff + 32);
      __syncthreads();                      // ph1
      __syncthreads();                      // ph2 (A computes h0)
      {
        const bf16x8 h0a = *(const bf16x8*)(H0 + aOff);
        const bf16x8 h0b = *(const bf16x8*)(H0 + aOff + 32);
        f32x4 g0 = MFMA16(WB[0],  h0a, bvB[0]); g0 = MFMA16(WB[1],  h0b, g0); g0 = MFMA16(WB[2],  fr0, g0); g0 = MFMA16(WB[3],  fr1, g0);
        f32x4 g1 = MFMA16(WB[4],  h0a, bvB[1]); g1 = MFMA16(WB[5],  h0b, g1); g1 = MFMA16(WB[6],  fr0, g1); g1 = MFMA16(WB[7],  fr1, g1);
        f32x4 g2 = MFMA16(WB[8],  h0a, bvB[2]); g2 = MFMA16(WB[9],  h0b, g2); g2 = MFMA16(WB[10], fr0, g2); g2 = MFMA16(WB[11], fr1, g2);
        f32x4 g3 = MFMA16(WB[12], h0a, bvB[3]); g3 = MFMA16(WB[13], h0b, g3); g3 = MFMA16(WB[14], fr0, g3); g3 = MFMA16(WB[15], fr1, g3);
        act4(g0, g1, g2, g3, H1);
      }
      __syncthreads();                      // ph3
      __syncthreads();                      // ph4 (A does FC head)
    }
  }
}

extern "C" void kernel_launch(void* const* d_in, const int* in_sizes, int n_in,
                              void* d_out, int out_size, void* d_ws, size_t ws_size,
                              hipStream_t stream) {
  (void)in_sizes; (void)n_in; (void)d_ws; (void)ws_size; (void)out_size;
  const void* x    = d_in[0];
  const void* Wih0 = d_in[1];
  const void* Whh0 = d_in[2];
  const void* bih0 = d_in[3];
  const void* bhh0 = d_in[4];
  const void* Wih1 = d_in[5];
  const void* Whh1 = d_in[6];
  const void* bih1 = d_in[7];
  const void* bhh1 = d_in[8];
  const void* fcw  = d_in[9];
  const void* fcb  = d_in[10];
  // Exactly one instance does the work (device-side dtype sniff).
  lstm2_pipe<true><<<dim3(4096 / NROWS), dim3(512), 0, stream>>>(
      x, Wih0, Whh0, bih0, bhh0, Wih1, Whh1, bih1, bhh1, fcw, fcb, d_out);
  lstm2_pipe<false><<<dim3(4096 / NROWS), dim3(512), 0, stream>>>(
      x, Wih0, Whh0, bih0, bhh0, Wih1, Whh1, bih1, bhh1, fcw, fcb, d_out);
}

// Round 5
// 873.008 us; speedup vs baseline: 1.6701x; 1.3121x over previous
//
#include <hip/hip_runtime.h>

#define T_SEQ   1024
#define INDIM   6
#define HDIM    64
#define NPRED   10
#define CHNK    128
#define S0      72       // LDS row stride (elements) for h buffers (h-only now)
#define NROWS   16       // batch rows per workgroup (grid 256 = 1 block/CU)

typedef __bf16         bf16x8 __attribute__((ext_vector_type(8)));
typedef float          f32x4  __attribute__((ext_vector_type(4)));
typedef float          f32x2  __attribute__((ext_vector_type(2)));
typedef unsigned short us4    __attribute__((ext_vector_type(4)));

// D = A*B + C with A = weight frag, B = h frag  ->  D[m=unit][n=batch row]
#define MFMA16(a, b, c) __builtin_amdgcn_mfma_f32_16x16x32_bf16((a), (b), (c), 0, 0, 0)

static __device__ __forceinline__ float bf2f(unsigned short b) {
  union { unsigned int u; float f; } v; v.u = ((unsigned int)b) << 16; return v.f;
}
// Native RNE f32->bf16 (ISel pairs these into v_cvt_pk_bf16_f32 on gfx950).
static __device__ __forceinline__ unsigned short f2bf(float f) {
  union { __bf16 b; unsigned short u; } v; v.b = (__bf16)f; return v.u;
}

// R5 = R1 skeleton (layer-pipelined, 1 barrier/encoder step, 512 thr) with:
//  - x staged as XB2[row][128][8] bf16 (2 zero pad lanes), XOR-swizzled
//    (t ^= row&7) on BOTH write and read; the layer-0 x-MFMA reads its
//    B-operand DIRECTLY from XB2 (q==0 lanes; q>0 broadcast-read ZPAD).
//    The per-step x copy (and its pathological 3-bank alias) is deleted.
//  - A0/A1 h-rows stride 104 -> 72 (16B-aligned, 8-window bank tiling).
//  - s_setprio(1/0) around each engine's MFMA cluster (wave role diversity).
// Decoder feedback preds go to XD[16][8]. Per-element math identical
// (bit-exact canary: absmax must stay 0.0009765625).
template <bool F32>
__global__ __launch_bounds__(512, 2)
void lstm2_pipe(const void* __restrict__ xv,
                const void* __restrict__ Wih0v,
                const void* __restrict__ Whh0v,
                const void* __restrict__ bih0v,
                const void* __restrict__ bhh0v,
                const void* __restrict__ Wih1v,
                const void* __restrict__ Whh1v,
                const void* __restrict__ bih1v,
                const void* __restrict__ bhh1v,
                const void* __restrict__ fcwv,
                const void* __restrict__ fcbv,
                void* __restrict__ outv)
{
  // ---- dtype sniff (uniform) ----
  {
    const unsigned short* w0u = (const unsigned short*)Wih0v;
    int votes = 0;
#pragma unroll
    for (int i = 0; i < 16; ++i) {
      const unsigned e = (w0u[2 * i] >> 7) & 0xFF;
      votes += (e >= 0x80 || e <= 0x40) ? 1 : 0;
    }
    if ((votes >= 4) != F32) return;
  }

  // A0[b]: [row][k]: k 0..63 = h0 (unit-major), 64..71 pad.
  __shared__ __align__(16) unsigned short A0[2][NROWS * S0];
  __shared__ __align__(16) unsigned short A1[2][NROWS * S0];
  __shared__ __align__(16) unsigned short XB2[NROWS * CHNK * 8];  // [row][t^ (row&7)][8]
  __shared__ __align__(16) unsigned short XD[NROWS * 8];          // decoder x feedback
  __shared__ __align__(16) unsigned short ZPAD[8];                // 16B of zeros
  __shared__ __align__(16) unsigned short FCW[INDIM * HDIM];
  __shared__ float FCB[INDIM];

  const int tid   = threadIdx.x;
  const int lane  = tid & 63;
  const int wave  = tid >> 6;
  const bool isA  = (wave < 4);
  const int  wv4  = wave & 3;
  const int  q    = lane >> 4;
  const int  n    = lane & 15;          // batch row owned by this lane (D col)
  const int  u    = 16 * wv4 + n;       // index used for W/bias row addressing
  const int rbase = blockIdx.x * NROWS;

  {
    unsigned short* p0 = &A0[0][0];
    unsigned short* p1 = &A1[0][0];
    for (int i = tid; i < 2 * NROWS * S0; i += 512) { p0[i] = 0; p1[i] = 0; }
    for (int i = tid; i < NROWS * 8; i += 512) XD[i] = 0;
    if (tid < 8) ZPAD[tid] = 0;
  }
  for (int i = tid; i < INDIM * HDIM; i += 512) {
    if constexpr (F32) FCW[i] = f2bf(((const float*)fcwv)[i]);
    else               FCW[i] = ((const unsigned short*)fcwv)[i];
  }
  if (tid < INDIM) {
    if constexpr (F32) FCB[tid] = ((const float*)fcbv)[tid];
    else               FCB[tid] = bf2f(((const unsigned short*)fcbv)[tid]);
  }

  auto ld1 = [&](const void* p, int i) -> float {
    if constexpr (F32) return ((const float*)p)[i];
    else               return bf2f(((const unsigned short*)p)[i]);
  };
  auto ld8 = [&](const void* W, int off) -> bf16x8 {
    union { unsigned short us[8]; bf16x8 v; } t;
    if constexpr (F32) {
      const float* p = (const float*)W + off;
#pragma unroll
      for (int j = 0; j < 8; ++j) t.us[j] = f2bf(p[j]);
    } else {
      t.v = *(const bf16x8*)((const unsigned short*)W + off);
    }
    return t.v;
  };

  // stage chunk [t0c, t0c+CHNK) into XB2: per (row,t): 6 x-values + 2 zeros,
  // swizzled slot t^(row&7). t fast-varying across lanes -> coalesced global.
  auto load_chunk = [&](int t0c) {
    for (int c = tid; c < NROWS * CHNK; c += 512) {
      const int row = c >> 7;          // 0..15
      const int t   = c & (CHNK - 1);  // 0..127
      int4 o;
      if constexpr (F32) {
        const float* p = (const float*)xv + ((size_t)(rbase + row) * T_SEQ + (t0c + t)) * INDIM;
        const float2 v0 = *(const float2*)(p);
        const float2 v1 = *(const float2*)(p + 2);
        const float2 v2 = *(const float2*)(p + 4);
        union { unsigned short us[8]; int4 v; } tt;
        tt.us[0] = f2bf(v0.x); tt.us[1] = f2bf(v0.y);
        tt.us[2] = f2bf(v1.x); tt.us[3] = f2bf(v1.y);
        tt.us[4] = f2bf(v2.x); tt.us[5] = f2bf(v2.y);
        tt.us[6] = 0;          tt.us[7] = 0;
        o = tt.v;
      } else {
        const unsigned short* p = (const unsigned short*)xv
            + ((size_t)(rbase + row) * T_SEQ + (t0c + t)) * INDIM;
        o.x = *(const unsigned int*)(p);
        o.y = *(const unsigned int*)(p + 2);
        o.z = *(const unsigned int*)(p + 4);
        o.w = 0;
      }
      *(int4*)((char*)XB2 + (((size_t)row * CHNK) + (t ^ (row & 7))) * 16) = o;
    }
  };

  load_chunk(0);

  // decoder FC/feedback mapping (tid-based, barrier-protected)
  const int dxr = tid / INDIM;                 // valid for tid < 96
  const int dxk = tid - dxr * INDIM;

  __syncthreads();   // covers zero-init + FCW + chunk 0

  const int aOff  = n * S0 + 8 * q;               // h frag (B-operand): row n, k 8q..
  const int hOffW = n * S0 + 16 * wv4 + 4 * q;    // packed h-write: row n, units 4q..4q+3
  const int bOff  = 16 * wv4 + 4 * q;             // bias vector base within gate block

  // x B-operand source: q==0 lanes read XB2 row n (swizzled), q>0 broadcast ZPAD
  auto xsrc_at = [&](int tc) -> const char* {
    return (q == 0)
        ? ((const char*)XB2 + (((size_t)n * CHNK) + (tc ^ (n & 7))) * 16)
        : (const char*)ZPAD;
  };

  // cell state as two f32 pairs (cells 0,1 | 2,3) so act math stays packed
  f32x2 cc2[2]; cc2[0] = (f32x2){0.f, 0.f}; cc2[1] = (f32x2){0.f, 0.f};

  // bias vector for gate block gt: b[64gt + bOff .. +3]
  auto ldbias = [&](const void* b1, const void* b2, int gt) -> f32x4 {
    f32x4 r;
#pragma unroll
    for (int j = 0; j < 4; ++j)
      r[j] = ld1(b1, 64 * gt + bOff + j) + ld1(b2, 64 * gt + bOff + j);
    return r;
  };

  // 7-trans combined-rcp cell update, packed-f32 (v_pk_*) elementwise math,
  // native cvt_pk bf16 packing, one b64 h-write.
  const f32x2 C1   = {-1.442695040888963f, -1.442695040888963f};
  const f32x2 C2   = {-2.885390081777927f, -2.885390081777927f};
  const f32x2 onep = {1.0f, 1.0f};

  auto act4 = [&](const f32x4 gI, const f32x4 gF, const f32x4 gG, const f32x4 gO,
                  unsigned short* dst) {
    unsigned int w2[2];
#pragma unroll
    for (int p = 0; p < 2; ++p) {
      f32x2 vI, vF, vG, vO;
      vI.x = gI[2 * p]; vI.y = gI[2 * p + 1];
      vF.x = gF[2 * p]; vF.y = gF[2 * p + 1];
      vG.x = gG[2 * p]; vG.y = gG[2 * p + 1];
      vO.x = gO[2 * p]; vO.y = gO[2 * p + 1];
      const f32x2 aF = vF * C1;
      const f32x2 aI = vI * C1;
      const f32x2 aG = vG * C2;
      const f32x2 aO = vO * C1;
      f32x2 Ae, Be, Ge, Oe;
      Ae.x = __builtin_amdgcn_exp2f(aF.x); Ae.y = __builtin_amdgcn_exp2f(aF.y);
      Be.x = __builtin_amdgcn_exp2f(aI.x); Be.y = __builtin_amdgcn_exp2f(aI.y);
      Ge.x = __builtin_amdgcn_exp2f(aG.x); Ge.y = __builtin_amdgcn_exp2f(aG.y);
      Oe.x = __builtin_amdgcn_exp2f(aO.x); Oe.y = __builtin_amdgcn_exp2f(aO.y);
      const f32x2 M1 = (onep + Be) * (onep + Ge);
      const f32x2 t2 = onep + Ae;
      const f32x2 nm = cc2[p] * M1 + (onep - Ge) * t2;
      const f32x2 den = t2 * M1;
      f32x2 rd; rd.x = __builtin_amdgcn_rcpf(den.x); rd.y = __builtin_amdgcn_rcpf(den.y);
      const f32x2 cn = nm * rd;
      cc2[p] = cn;
      const f32x2 aE = cn * C2;
      f32x2 Ee; Ee.x = __builtin_amdgcn_exp2f(aE.x); Ee.y = __builtin_amdgcn_exp2f(aE.y);
      const f32x2 dh = (onep + Ee) * (onep + Oe);
      f32x2 rh; rh.x = __builtin_amdgcn_rcpf(dh.x); rh.y = __builtin_amdgcn_rcpf(dh.y);
      const f32x2 hv = (onep - Ee) * rh;
      w2[p] = (unsigned int)f2bf(hv.x) | ((unsigned int)f2bf(hv.y) << 16);
    }
    uint2 pk; pk.x = w2[0]; pk.y = w2[1];
    *(uint2*)(dst + hOffW) = pk;
  };

  unsigned short* H0 = &A0[0][0];    // after encoder: h0(1023)
  unsigned short* H1 = &A1[1][0];    // after encoder: h1(1023)

  if (isA) {
    // ================= layer-0 engine =================
    bf16x8 WA[12]; f32x4 bvA[4];
#pragma unroll
    for (int gt = 0; gt < 4; ++gt) {
      const int col = 64 * gt + u;
      WA[gt * 3 + 0] = ld8(Whh0v, col * HDIM + 8 * q);       // A-frag: W[unit][k]
      WA[gt * 3 + 1] = ld8(Whh0v, col * HDIM + 32 + 8 * q);
      union { unsigned short us[8]; bf16x8 v; } t2;
#pragma unroll
      for (int j = 0; j < 8; ++j) t2.us[j] = 0;
      if (q == 0) {
#pragma unroll
        for (int j = 0; j < INDIM; ++j) t2.us[j] = f2bf(ld1(Wih0v, col * INDIM + j));
      }
      WA[gt * 3 + 2] = t2.v;
      bvA[gt] = ldbias(bih0v, bhh0v, gt);
    }

    int t0v = 0;
    for (int i = 0; i <= T_SEQ; ++i) {
      if (i > 0 && i < T_SEQ && (i & (CHNK - 1)) == 0) {
        load_chunk(i);            // prior step's XB2 reads are behind last barrier
        __syncthreads();
        t0v = i;
      }
      const int cur = i & 1;
      if (i < T_SEQ) {
        const unsigned short* A0c = &A0[cur][0];
        unsigned short*       A0n = &A0[cur ^ 1][0];
        const bf16x8 f0 = *(const bf16x8*)(A0c + aOff);
        const bf16x8 f1 = *(const bf16x8*)(A0c + aOff + 32);
        const bf16x8 f2 = *(const bf16x8*)(xsrc_at(i - t0v));
        __builtin_amdgcn_s_setprio(1);
        f32x4 g0 = MFMA16(WA[0], f0, bvA[0]); g0 = MFMA16(WA[1],  f1, g0); g0 = MFMA16(WA[2],  f2, g0);
        f32x4 g1 = MFMA16(WA[3], f0, bvA[1]); g1 = MFMA16(WA[4],  f1, g1); g1 = MFMA16(WA[5],  f2, g1);
        f32x4 g2 = MFMA16(WA[6], f0, bvA[2]); g2 = MFMA16(WA[7],  f1, g2); g2 = MFMA16(WA[8],  f2, g2);
        f32x4 g3 = MFMA16(WA[9], f0, bvA[3]); g3 = MFMA16(WA[10], f1, g3); g3 = MFMA16(WA[11], f2, g3);
        __builtin_amdgcn_s_setprio(0);
        act4(g0, g1, g2, g3, A0n);
      }
      __syncthreads();
    }
    // seed decoder x feedback with x(1023) (last chunk t0v=896, tc=127)
    if (tid < 96)
      XD[dxr * 8 + dxk] = XB2[((size_t)dxr * CHNK + (127 ^ (dxr & 7))) * 8 + dxk];
    __syncthreads();
    // decoder, engine A (4 barriers/step, mirrored in B)
    for (int d = 0; d < NPRED; ++d) {
      const bf16x8 fa0 = *(const bf16x8*)(H0 + aOff);
      const bf16x8 fa1 = *(const bf16x8*)(H0 + aOff + 32);
      const bf16x8 fa2 = *(const bf16x8*)((q == 0) ? ((const char*)XD + n * 16)
                                                   : (const char*)ZPAD);
      __syncthreads();                      // ph1
      {
        f32x4 g0 = MFMA16(WA[0], fa0, bvA[0]); g0 = MFMA16(WA[1],  fa1, g0); g0 = MFMA16(WA[2],  fa2, g0);
        f32x4 g1 = MFMA16(WA[3], fa0, bvA[1]); g1 = MFMA16(WA[4],  fa1, g1); g1 = MFMA16(WA[5],  fa2, g1);
        f32x4 g2 = MFMA16(WA[6], fa0, bvA[2]); g2 = MFMA16(WA[7],  fa1, g2); g2 = MFMA16(WA[8],  fa2, g2);
        f32x4 g3 = MFMA16(WA[9], fa0, bvA[3]); g3 = MFMA16(WA[10], fa1, g3); g3 = MFMA16(WA[11], fa2, g3);
        act4(g0, g1, g2, g3, H0);
      }
      __syncthreads();                      // ph2
      __syncthreads();                      // ph3 (B computes h1)
      if (tid < 96) {                       // ph4: FC head + feedback
        const unsigned short* h1row = H1 + dxr * S0;
        const int4* hp = (const int4*)h1row;
        const int4* wp = (const int4*)(&FCW[dxk * HDIM]);
        float s = FCB[dxk];
#pragma unroll
        for (int i8 = 0; i8 < 8; ++i8) {
          const int4 hv = hp[i8];
          const int4 wv2 = wp[i8];
          const unsigned int hu[4] = {(unsigned)hv.x, (unsigned)hv.y, (unsigned)hv.z, (unsigned)hv.w};
          const unsigned int wu[4] = {(unsigned)wv2.x, (unsigned)wv2.y, (unsigned)wv2.z, (unsigned)wv2.w};
#pragma unroll
          for (int k2 = 0; k2 < 4; ++k2) {
            union { unsigned int uu; float ff; } hl, hh2, wl, wh;
            hl.uu = hu[k2] << 16; hh2.uu = hu[k2] & 0xFFFF0000u;
            wl.uu = wu[k2] << 16; wh.uu  = wu[k2] & 0xFFFF0000u;
            s += hl.ff * wl.ff + hh2.ff * wh.ff;
          }
        }
        const unsigned short pb = f2bf(s);
        const size_t idx = (size_t)(rbase + dxr) * (NPRED * INDIM) + (size_t)d * INDIM + dxk;
        if constexpr (F32) ((float*)outv)[idx] = s;
        else               ((unsigned short*)outv)[idx] = pb;
        XD[dxr * 8 + dxk] = pb;
      }
      __syncthreads();                      // ph4 end
    }
  } else {
    // ================= layer-1 engine (lag 1) =================
    bf16x8 WB[16]; f32x4 bvB[4];
#pragma unroll
    for (int gt = 0; gt < 4; ++gt) {
      const int col = 64 * gt + u;
      WB[gt * 4 + 0] = ld8(Wih1v, col * HDIM + 8 * q);
      WB[gt * 4 + 1] = ld8(Wih1v, col * HDIM + 32 + 8 * q);
      WB[gt * 4 + 2] = ld8(Whh1v, col * HDIM + 8 * q);
      WB[gt * 4 + 3] = ld8(Whh1v, col * HDIM + 32 + 8 * q);
      bvB[gt] = ldbias(bih1v, bhh1v, gt);
    }

    for (int i = 0; i <= T_SEQ; ++i) {
      if (i > 0 && i < T_SEQ && (i & (CHNK - 1)) == 0) {
        load_chunk(i);
        __syncthreads();
      }
      const int cur = i & 1;
      if (i >= 1) {
        const unsigned short* A0c = &A0[cur][0];
        const unsigned short* A1c = &A1[cur][0];
        unsigned short*       A1n = &A1[cur ^ 1][0];
        const bf16x8 h0a = *(const bf16x8*)(A0c + aOff);
        const bf16x8 h0b = *(const bf16x8*)(A0c + aOff + 32);
        const bf16x8 r0  = *(const bf16x8*)(A1c + aOff);
        const bf16x8 r1  = *(const bf16x8*)(A1c + aOff + 32);
        __builtin_amdgcn_s_setprio(1);
        f32x4 g0 = MFMA16(WB[0],  h0a, bvB[0]); g0 = MFMA16(WB[1],  h0b, g0); g0 = MFMA16(WB[2],  r0, g0); g0 = MFMA16(WB[3],  r1, g0);
        f32x4 g1 = MFMA16(WB[4],  h0a, bvB[1]); g1 = MFMA16(WB[5],  h0b, g1); g1 = MFMA16(WB[6],  r0, g1); g1 = MFMA16(WB[7],  r1, g1);
        f32x4 g2 = MFMA16(WB[8],  h0a, bvB[2]); g2 = MFMA16(WB[9],  h0b, g2); g2 = MFMA16(WB[10], r0, g2); g2 = MFMA16(WB[11], r1, g2);
        f32x4 g3 = MFMA16(WB[12], h0a, bvB[3]); g3 = MFMA16(WB[13], h0b, g3); g3 = MFMA16(WB[14], r0, g3); g3 = MFMA16(WB[15], r1, g3);
        __builtin_amdgcn_s_setprio(0);
        act4(g0, g1, g2, g3, A1n);
      }
      __syncthreads();
    }
    __syncthreads();   // matches A's XD-seed barrier
    // decoder, engine B (4 barriers/step, mirrored with A)
    for (int d = 0; d < NPRED; ++d) {
      const bf16x8 fr0 = *(const bf16x8*)(H1 + aOff);
      const bf16x8 fr1 = *(const bf16x8*)(H1 + aOff + 32);
      __syncthreads();                      // ph1
      __syncthreads();                      // ph2 (A computes h0)
      {
        const bf16x8 h0a = *(const bf16x8*)(H0 + aOff);
        const bf16x8 h0b = *(const bf16x8*)(H0 + aOff + 32);
        f32x4 g0 = MFMA16(WB[0],  h0a, bvB[0]); g0 = MFMA16(WB[1],  h0b, g0); g0 = MFMA16(WB[2],  fr0, g0); g0 = MFMA16(WB[3],  fr1, g0);
        f32x4 g1 = MFMA16(WB[4],  h0a, bvB[1]); g1 = MFMA16(WB[5],  h0b, g1); g1 = MFMA16(WB[6],  fr0, g1); g1 = MFMA16(WB[7],  fr1, g1);
        f32x4 g2 = MFMA16(WB[8],  h0a, bvB[2]); g2 = MFMA16(WB[9],  h0b, g2); g2 = MFMA16(WB[10], fr0, g2); g2 = MFMA16(WB[11], fr1, g2);
        f32x4 g3 = MFMA16(WB[12], h0a, bvB[3]); g3 = MFMA16(WB[13], h0b, g3); g3 = MFMA16(WB[14], fr0, g3); g3 = MFMA16(WB[15], fr1, g3);
        act4(g0, g1, g2, g3, H1);
      }
      __syncthreads();                      // ph3
      __syncthreads();                      // ph4 (A does FC head)
    }
  }
}

extern "C" void kernel_launch(void* const* d_in, const int* in_sizes, int n_in,
                              void* d_out, int out_size, void* d_ws, size_t ws_size,
                              hipStream_t stream) {
  (void)in_sizes; (void)n_in; (void)d_ws; (void)ws_size; (void)out_size;
  const void* x    = d_in[0];
  const void* Wih0 = d_in[1];
  const void* Whh0 = d_in[2];
  const void* bih0 = d_in[3];
  const void* bhh0 = d_in[4];
  const void* Wih1 = d_in[5];
  const void* Whh1 = d_in[6];
  const void* bih1 = d_in[7];
  const void* bhh1 = d_in[8];
  const void* fcw  = d_in[9];
  const void* fcb  = d_in[10];
  // Exactly one instance does the work (device-side dtype sniff).
  lstm2_pipe<true><<<dim3(4096 / NROWS), dim3(512), 0, stream>>>(
      x, Wih0, Whh0, bih0, bhh0, Wih1, Whh1, bih1, bhh1, fcw, fcb, d_out);
  lstm2_pipe<false><<<dim3(4096 / NROWS), dim3(512), 0, stream>>>(
      x, Wih0, Whh0, bih0, bhh0, Wih1, Whh1, bih1, bhh1, fcw, fcb, d_out);
}